// Round 1
// baseline (1261.925 us; speedup 1.0000x reference)
//
#include <hip/hip_runtime.h>
#include <hip/hip_bf16.h>
#include <math.h>

// TemporalAttention: T=512, N=1024, D=256
//   e = score_w . tanh(H @ fc_w^T + fc_b)            (bf16 MFMA GEMM, fused epilogue)
//   coefficients A_t = alpha*s_{t-1}/s_t, B_t = p_t/s_t   (tiny scalar scan)
//   C[t] = A_t*C[t-1] + B_t*H[t]                     (streaming FMA scan)

#define T_DIM 512
#define N_DIM 1024
#define D_DIM 256

typedef short v8s __attribute__((ext_vector_type(8)));   // 8 bf16 (4 VGPRs)
typedef float v4f __attribute__((ext_vector_type(4)));   // 4 fp32 acc

__device__ __forceinline__ unsigned pk_bf16(float a, float b) {
    // RNE fp32->bf16, packed pair (b in high 16)
    unsigned ua = __builtin_bit_cast(unsigned, a);
    unsigned ub = __builtin_bit_cast(unsigned, b);
    ua = ua + 0x7fffu + ((ua >> 16) & 1u);
    ub = ub + 0x7fffu + ((ub >> 16) & 1u);
    return (ua >> 16) | (ub & 0xffff0000u);
}

__device__ __forceinline__ float fast_tanh(float x) {
    // tanh(x) = 1 - 2/(exp(2x)+1); handles +-inf limits correctly
    float e = __expf(2.0f * x);
    return 1.0f - 2.0f / (e + 1.0f);
}

// ---------------------------------------------------------------------------
// Kernel 1: e[t*N+n] = score_w . tanh(H_row @ fc_w^T + fc_b)
// Persistent-B design: wave w holds B-frags for j in [w*64, w*64+64) in regs.
// A-frags loaded straight from global (16 rows x 128B contiguous per k-step).
// ---------------------------------------------------------------------------
__global__ __launch_bounds__(256, 2) void k_score(
    const float* __restrict__ H, const float* __restrict__ fc_w,
    const float* __restrict__ fc_b, const float* __restrict__ score_w,
    float* __restrict__ e_out)
{
    const int tid  = threadIdx.x;
    const int w    = tid >> 6;       // wave 0..3
    const int l    = tid & 63;
    const int l15  = l & 15;
    const int quad = l >> 4;

    // --- persistent B fragments: Bf[jt][ks], j = w*64 + jt*16 + l15 ---
    v8s Bf[4][8];
#pragma unroll
    for (int jt = 0; jt < 4; ++jt) {
        const int j = w * 64 + jt * 16 + l15;
#pragma unroll
        for (int ks = 0; ks < 8; ++ks) {
            const int k = ks * 32 + quad * 8;
            const float4* p = (const float4*)(fc_w + j * D_DIM + k);
            float4 b0 = p[0], b1 = p[1];
            union { v8s v; unsigned u[4]; } bf;
            bf.u[0] = pk_bf16(b0.x, b0.y); bf.u[1] = pk_bf16(b0.z, b0.w);
            bf.u[2] = pk_bf16(b1.x, b1.y); bf.u[3] = pk_bf16(b1.z, b1.w);
            Bf[jt][ks] = bf.v;
        }
    }
    float fcb[4], scw[4];
#pragma unroll
    for (int jt = 0; jt < 4; ++jt) {
        const int j = w * 64 + jt * 16 + l15;
        fcb[jt] = fc_b[j];
        scw[jt] = score_w[j];
    }

    __shared__ float ebuf[4][16];

    const int n_tiles = (T_DIM * N_DIM) / 16;   // 32768 row-tiles of 16
    for (int mt = blockIdx.x; mt < n_tiles; mt += gridDim.x) {
        const float* hrow = H + (size_t)(mt * 16 + l15) * D_DIM + quad * 8;

        v4f acc[4];
        const v4f vz = {0.f, 0.f, 0.f, 0.f};
#pragma unroll
        for (int jt = 0; jt < 4; ++jt) acc[jt] = vz;

#pragma unroll
        for (int ks = 0; ks < 8; ++ks) {
            const float4* p = (const float4*)(hrow + ks * 32);
            float4 h0 = p[0], h1 = p[1];
            union { v8s v; unsigned u[4]; } af;
            af.u[0] = pk_bf16(h0.x, h0.y); af.u[1] = pk_bf16(h0.z, h0.w);
            af.u[2] = pk_bf16(h1.x, h1.y); af.u[3] = pk_bf16(h1.z, h1.w);
#pragma unroll
            for (int jt = 0; jt < 4; ++jt)
                acc[jt] = __builtin_amdgcn_mfma_f32_16x16x32_bf16(
                    af.v, Bf[jt][ks], acc[jt], 0, 0, 0);
        }

        // epilogue: tanh, score-weight, reduce over j
        // C/D layout: col(j) = l15, row = quad*4 + r
        float er[4];
#pragma unroll
        for (int r = 0; r < 4; ++r) {
            float s = 0.f;
#pragma unroll
            for (int jt = 0; jt < 4; ++jt) {
                float q = fast_tanh(acc[jt][r] + fcb[jt]);
                s += q * scw[jt];
            }
            er[r] = s;
        }
#pragma unroll
        for (int m = 1; m < 16; m <<= 1) {
#pragma unroll
            for (int r = 0; r < 4; ++r)
                er[r] += __shfl_xor(er[r], m, 64);
        }
        if (l15 == 0) {
#pragma unroll
            for (int r = 0; r < 4; ++r) ebuf[w][quad * 4 + r] = er[r];
        }
        __syncthreads();
        if (tid < 16) {
            float ev = ebuf[0][tid] + ebuf[1][tid] + ebuf[2][tid] + ebuf[3][tid];
            e_out[mt * 16 + tid] = ev;
        }
        __syncthreads();
    }
}

// ---------------------------------------------------------------------------
// Kernel 2: per-n online-softmax scan -> coefficients (A_t, B_t) packed float2
// ---------------------------------------------------------------------------
__global__ void k_coef(const float* __restrict__ e, float2* __restrict__ co)
{
    const int n = blockIdx.x * blockDim.x + threadIdx.x;   // 0..1023
    float m = -INFINITY, s = 0.f;
    for (int t = 0; t < T_DIM; ++t) {
        float ev    = e[t * N_DIM + n];
        float mn    = fmaxf(m, ev);
        float alpha = __expf(m - mn);    // m=-inf first iter -> 0
        float p     = __expf(ev - mn);
        float sn    = s * alpha + p;
        float rs    = 1.0f / sn;
        co[t * N_DIM + n] = make_float2(alpha * s * rs, p * rs);
        m = mn; s = sn;
    }
}

// ---------------------------------------------------------------------------
// Kernel 3: streaming scan  C[t,n,:] = A_t*C[t-1,n,:] + B_t*H[t,n,:]
// one block (128 thr, float2/thread) per n-column; coefficients are
// block-uniform (scalar loads); 1-deep prefetch.
// ---------------------------------------------------------------------------
__global__ __launch_bounds__(128) void k_apply(
    const float* __restrict__ H, const float2* __restrict__ co,
    float* __restrict__ C)
{
    const int n  = blockIdx.x;
    const int d2 = threadIdx.x;                     // float2 index within row
    const float2* Hp = (const float2*)(H + (size_t)n * D_DIM) + d2;
    float2*       Cp = (float2*)(C + (size_t)n * D_DIM) + d2;
    const int stride2 = (N_DIM * D_DIM) / 2;        // t-stride in float2

    float2 num = {0.f, 0.f};
    float2 h   = Hp[0];
    float2 ab  = co[n];
    for (int t = 0; t < T_DIM; ++t) {
        float2 hn = {0.f, 0.f};
        float2 abn = {0.f, 0.f};
        if (t + 1 < T_DIM) {
            hn  = Hp[(size_t)(t + 1) * stride2];
            abn = co[(t + 1) * N_DIM + n];
        }
        num.x = num.x * ab.x + ab.y * h.x;
        num.y = num.y * ab.x + ab.y * h.y;
        Cp[(size_t)t * stride2] = num;
        h = hn; ab = abn;
    }
}

// ---------------------------------------------------------------------------
extern "C" void kernel_launch(void* const* d_in, const int* in_sizes, int n_in,
                              void* d_out, int out_size, void* d_ws, size_t ws_size,
                              hipStream_t stream) {
    const float* H       = (const float*)d_in[0];
    const float* fc_w    = (const float*)d_in[1];
    const float* fc_b    = (const float*)d_in[2];
    const float* score_w = (const float*)d_in[3];
    float* C = (float*)d_out;

    float*  e  = (float*)d_ws;                         // 2 MB
    float2* co = (float2*)(e + T_DIM * N_DIM);         // 4 MB

    k_score<<<dim3(512), dim3(256), 0, stream>>>(H, fc_w, fc_b, score_w, e);
    k_coef <<<dim3(4),   dim3(256), 0, stream>>>(e, co);
    k_apply<<<dim3(N_DIM), dim3(128), 0, stream>>>(H, co, C);
}